// Round 1
// 294.936 us; speedup vs baseline: 1.0386x; 1.0386x over previous
//
#include <hip/hip_runtime.h>
#include <hip/hip_bf16.h>

#define N_NODES 50000
#define N_PAD   50048
#define N_EDGES 600000
#define IN_CH 128
#define HID 256
#define OUT_CH 128

typedef unsigned short u16;
typedef unsigned char u8;
typedef unsigned int u32;

typedef __attribute__((ext_vector_type(8))) short short8;
typedef __attribute__((ext_vector_type(4))) float f32x4;

typedef __attribute__((address_space(3))) u32 as3_u32;
typedef __attribute__((address_space(1))) const u32 as1_u32;

__device__ __forceinline__ float bf2f(u16 v) {
    unsigned u = ((unsigned)v) << 16;
    return __uint_as_float(u);
}
__device__ __forceinline__ u16 f2bf(float f) {
    unsigned u = __float_as_uint(f);
    u += 0x7FFF + ((u >> 16) & 1);   // round-to-nearest-even
    return (u16)(u >> 16);
}

// tanh(x) = 1 - 2/(e^{2x}+1); e^{2x} = 2^{x*2.885390}. 4 VALU ops vs ~25 for tanhf.
// Saturates correctly: exp2(+big)=inf -> 1; exp2(-big)=0 -> -1. abs err ~1e-7 << bf16 ulp.
__device__ __forceinline__ float fast_tanh(float x) {
    float e = __builtin_amdgcn_exp2f(x * 2.88539008177793f);
    return 1.f - 2.f * __builtin_amdgcn_rcpf(e + 1.f);
}

// async global->LDS, 16B per lane; LDS dest = wave-uniform base + lane*16
__device__ __forceinline__ void async16(const void* g, void* l) {
    __builtin_amdgcn_global_load_lds((as1_u32*)g, (as3_u32*)l, 16, 0, 0);
}

// ---------------- format detection (one wave, lane-parallel) ----------------
// flags[0]: 1 if float tensors are bf16, 0 if f32
// flags[1]: mask format: 0=u8, 1=i32, 2=f32, 3=bf16
__global__ void detect_kernel(const u16* __restrict__ xu, const u8* __restrict__ mb,
                              int* __restrict__ flags) {
    int lane = threadIdx.x & 63;

    int inr = 0;
    {
        u32 w0 = ((const u32*)xu)[lane * 2 + 0];
        u32 w1 = ((const u32*)xu)[lane * 2 + 1];
        u16 h[4] = {(u16)w0, (u16)(w0 >> 16), (u16)w1, (u16)(w1 >> 16)};
#pragma unroll
        for (int j = 0; j < 4; j++) {
            int e = (h[j] >> 7) & 0xFF;
            if (e >= 100 && e <= 133) inr++;
        }
    }

    int c1 = 0, c23 = 0, h3f_1 = 0, h3f_3 = 0;
#pragma unroll
    for (int t = 0; t < 16; t++) {
        u32 w = ((const u32*)mb)[t * 64 + lane];
        u8 b1 = (u8)(w >> 8), b2 = (u8)(w >> 16), b3 = (u8)(w >> 24);
        if (b1) c1++;
        if (b1 == 0x3F) h3f_1 = 1;
        if (b2) c23++;
        if (b3) c23++;
        if (b3 == 0x3F) h3f_3 = 1;
    }

#pragma unroll
    for (int off = 32; off > 0; off >>= 1) {
        inr   += __shfl_xor(inr, off, 64);
        c1    += __shfl_xor(c1, off, 64);
        c23   += __shfl_xor(c23, off, 64);
        h3f_1 |= __shfl_xor(h3f_1, off, 64);
        h3f_3 |= __shfl_xor(h3f_3, off, 64);
    }

    if (lane == 0 && blockIdx.x == 0) {
        flags[0] = (inr >= 200) ? 1 : 0;
        int fmt;
        if (h3f_1) fmt = 3;              // bf16
        else if (h3f_3) fmt = 2;         // f32
        else if (c1 + c23 > 0) fmt = 0;  // u8 bool
        else fmt = 1;                    // int32
        flags[1] = fmt;
    }
}

// ---------------- fused conversion: x + all weight concats + biases + degp zero ----------------
#define NX (N_NODES * IN_CH)
#define DEGP_N 50176
__global__ void convert_all_kernel(const void* __restrict__ x,
                                   const void* __restrict__ W1l, const void* __restrict__ W1r,
                                   const void* __restrict__ Ws,
                                   const void* __restrict__ W2l, const void* __restrict__ W2r,
                                   const void* __restrict__ Wo,
                                   const void* __restrict__ b1, const void* __restrict__ bs,
                                   const void* __restrict__ b2, const void* __restrict__ bo,
                                   u16* __restrict__ xb, u16* __restrict__ Wc1,
                                   u16* __restrict__ Wsb, u16* __restrict__ Wc2,
                                   u16* __restrict__ Wob, float* __restrict__ biasf,
                                   u32* __restrict__ degp,
                                   const int* __restrict__ flags) {
    int i = blockIdx.x * blockDim.x + threadIdx.x;
    int isbf = flags[0];
    auto cv = [&](const void* s, int idx) -> u16 {
        return isbf ? ((const u16*)s)[idx] : f2bf(((const float*)s)[idx]);
    };
    if (i < NX) { xb[i] = cv(x, i); return; }
    i -= NX;
    if (i < 256 * 256) {                       // Wc1 = [W1l | W1r] along k
        int n = i >> 8, k = i & 255;
        const void* s = (k < 128) ? W1l : W1r;
        Wc1[i] = cv(s, n * 128 + (k & 127));
        return;
    }
    i -= 256 * 256;
    if (i < 256 * 128) { Wsb[i] = cv(Ws, i); return; }
    i -= 256 * 128;
    if (i < 256 * 512) {                       // Wc2 = [W2l | W2r] along k
        int n = i >> 9, k = i & 511;
        const void* s = (k < 256) ? W2l : W2r;
        Wc2[i] = cv(s, n * 256 + (k & 255));
        return;
    }
    i -= 256 * 512;
    if (i < 128 * 256) { Wob[i] = cv(Wo, i); return; }
    i -= 128 * 256;
    if (i < 896) {
        const void* s; int idx;
        if (i < 256)      { s = b1; idx = i; }
        else if (i < 512) { s = bs; idx = i - 256; }
        else if (i < 768) { s = b2; idx = i - 512; }
        else              { s = bo; idx = i - 768; }
        biasf[i] = isbf ? bf2f(((const u16*)s)[idx]) : ((const float*)s)[idx];
        return;
    }
    i -= 896;
    if (i < DEGP_N) degp[i] = 0;              // replaces separate hipMemsetAsync
}
#define CONV_TOTAL (NX + 256 * 256 + 256 * 128 + 256 * 512 + 128 * 256 + 896 + DEGP_N)

// ---------------- CSR build: packed dual histogram (deg lo16 | deg2 hi16) ----------------
__global__ void hist_kernel(const int* __restrict__ ei, const void* __restrict__ em,
                            u32* __restrict__ degp, u32* __restrict__ rankp,
                            const int* __restrict__ flags) {
    int i = blockIdx.x * blockDim.x + threadIdx.x;
    if (i >= N_EDGES) return;
    int d = ei[N_EDGES + i];
    int fmt = flags[1];
    bool keep;
    if (fmt == 0)      keep = ((const u8*)em)[i] != 0;
    else if (fmt == 1) keep = ((const int*)em)[i] != 0;
    else if (fmt == 2) keep = ((const float*)em)[i] != 0.f;
    else               keep = ((const u16*)em)[i] != 0;
    u32 inc = keep ? 0x10001u : 1u;
    u32 old = atomicAdd(&degp[d], inc);        // ONE atomic yields both ranks
    rankp[i] = (old & 0xffffu) | (keep ? (old & 0xffff0000u) : 0xffff0000u);
}

// packed per-chunk totals (chunk sums < 65536 per half -> no cross-carry)
__global__ void partial_kernel(const u32* __restrict__ degp, u32* __restrict__ partial) {
    __shared__ u32 sh[256];
    int t = threadIdx.x;
    int i = blockIdx.x * 256 + t;
    sh[t] = (i < N_NODES) ? degp[i] : 0;
    __syncthreads();
    for (int s = 128; s > 0; s >>= 1) {
        if (t < s) sh[t] += sh[t + s];
        __syncthreads();
    }
    if (t == 0) partial[blockIdx.x] = sh[0];
}

// one block: unpack chunk totals, exclusive-scan both halves -> pscan[0..nb) / pscan[nb..2nb)
__global__ void scanp_kernel(const u32* __restrict__ partial, int* __restrict__ pscan, int nb) {
    __shared__ int sh[256];
    int t = threadIdx.x;
    u32 pv = (t < nb) ? partial[t] : 0;
    int v1 = pv & 0xffff, v2 = pv >> 16;
    sh[t] = v1;
    __syncthreads();
    for (int o = 1; o < 256; o <<= 1) {
        int u = (t >= o) ? sh[t - o] : 0;
        __syncthreads();
        sh[t] += u;
        __syncthreads();
    }
    if (t < nb) pscan[t] = sh[t] - v1;
    __syncthreads();
    sh[t] = v2;
    __syncthreads();
    for (int o = 1; o < 256; o <<= 1) {
        int u = (t >= o) ? sh[t - o] : 0;
        __syncthreads();
        sh[t] += u;
        __syncthreads();
    }
    if (t < nb) pscan[nb + t] = sh[t] - v2;
}

// packed intra-chunk scan + global offsets -> both row_ptrs in one pass
__global__ void rowptr_kernel(const u32* __restrict__ degp, const int* __restrict__ pscan,
                              int* __restrict__ row_ptr, int* __restrict__ row_ptr2, int nb) {
    __shared__ u32 sh[256];
    int t = threadIdx.x;
    int i = blockIdx.x * 256 + t;
    u32 v = (i < N_NODES) ? degp[i] : 0;
    sh[t] = v;
    __syncthreads();
    for (int o = 1; o < 256; o <<= 1) {
        u32 u = (t >= o) ? sh[t - o] : 0;
        __syncthreads();
        sh[t] += u;
        __syncthreads();
    }
    u32 ex = sh[t] - v;                        // packed exclusive scan
    if (i <= N_NODES) {
        row_ptr[i]  = pscan[blockIdx.x] + (int)(ex & 0xffff);
        row_ptr2[i] = pscan[nb + blockIdx.x] + (int)(ex >> 16);
    }
}

__global__ void scatter_csr_kernel(const int* __restrict__ ei, const u32* __restrict__ rankp,
                                   const int* __restrict__ row_ptr, const int* __restrict__ row_ptr2,
                                   int* __restrict__ srcs, int* __restrict__ srcs2) {
    int i = blockIdx.x * blockDim.x + threadIdx.x;
    if (i >= N_EDGES) return;
    int d = ei[N_EDGES + i];
    int s = ei[i];
    u32 rp = rankp[i];
    srcs[row_ptr[d] + (int)(rp & 0xffffu)] = s;
    u32 kr = rp >> 16;
    if (kr != 0xffffu) srcs2[row_ptr2[d] + (int)kr] = s;
}

// ---------------- CSR gathers: scalar-addressed via lane-preload + readlane ----------------
__global__ __launch_bounds__(256) void gather1_kernel(const int* __restrict__ row_ptr,
                                                      const int* __restrict__ srcs,
                                                      const u16* __restrict__ xb,
                                                      u16* __restrict__ aggb) {
    int wid = (blockIdx.x * blockDim.x + threadIdx.x) >> 6;
    int lane = threadIdx.x & 63;
    if (wid >= N_NODES) return;
    int start = row_ptr[wid], end = row_ptr[wid + 1];
    int dg = end - start;
    int sv = (lane < dg) ? srcs[start + lane] : 0;   // one coalesced preload
    float a0 = 0.f, a1 = 0.f, b0 = 0.f, b1 = 0.f;
    float c0 = 0.f, c1 = 0.f, d0 = 0.f, d1 = 0.f;
    int n = dg < 64 ? dg : 64;
    int e = 0;
    for (; e + 4 <= n; e += 4) {
        int s0 = __builtin_amdgcn_readlane(sv, e);
        int s1 = __builtin_amdgcn_readlane(sv, e + 1);
        int s2 = __builtin_amdgcn_readlane(sv, e + 2);
        int s3 = __builtin_amdgcn_readlane(sv, e + 3);
        u32 v0 = *(const u32*)(xb + (size_t)s0 * IN_CH + lane * 2);
        u32 v1 = *(const u32*)(xb + (size_t)s1 * IN_CH + lane * 2);
        u32 v2 = *(const u32*)(xb + (size_t)s2 * IN_CH + lane * 2);
        u32 v3 = *(const u32*)(xb + (size_t)s3 * IN_CH + lane * 2);
        a0 += bf2f((u16)v0); a1 += bf2f((u16)(v0 >> 16));
        b0 += bf2f((u16)v1); b1 += bf2f((u16)(v1 >> 16));
        c0 += bf2f((u16)v2); c1 += bf2f((u16)(v2 >> 16));
        d0 += bf2f((u16)v3); d1 += bf2f((u16)(v3 >> 16));
    }
    for (; e < n; e++) {
        int s0 = __builtin_amdgcn_readlane(sv, e);
        u32 v0 = *(const u32*)(xb + (size_t)s0 * IN_CH + lane * 2);
        a0 += bf2f((u16)v0); a1 += bf2f((u16)(v0 >> 16));
    }
    for (e = 64; e < dg; e++) {                      // rare tail (deg>64)
        int s0 = srcs[start + e];
        u32 v0 = *(const u32*)(xb + (size_t)s0 * IN_CH + lane * 2);
        a0 += bf2f((u16)v0); a1 += bf2f((u16)(v0 >> 16));
    }
    float inv = 1.f / fmaxf((float)dg, 1.f);
    float rx = (a0 + b0) + (c0 + d0);
    float ry = (a1 + b1) + (c1 + d1);
    u32 o = (u32)f2bf(rx * inv) | ((u32)f2bf(ry * inv) << 16);
    *(u32*)(aggb + (size_t)wid * IN_CH + lane * 2) = o;
}

__global__ __launch_bounds__(256) void gather2_kernel(const int* __restrict__ row_ptr2,
                                                      const int* __restrict__ srcs2,
                                                      const u16* __restrict__ h1b,
                                                      u16* __restrict__ aggb) {
    int wid = (blockIdx.x * blockDim.x + threadIdx.x) >> 6;
    int lane = threadIdx.x & 63;
    if (wid >= N_NODES) return;
    int start = row_ptr2[wid], end = row_ptr2[wid + 1];
    int dg = end - start;
    int sv = (lane < dg) ? srcs2[start + lane] : 0;
    float a0 = 0.f, a1 = 0.f, a2 = 0.f, a3 = 0.f;
    float b0 = 0.f, b1 = 0.f, b2 = 0.f, b3 = 0.f;
    float c0 = 0.f, c1 = 0.f, c2 = 0.f, c3 = 0.f;
    float d0 = 0.f, d1 = 0.f, d2 = 0.f, d3 = 0.f;
    int n = dg < 64 ? dg : 64;
    int e = 0;
    for (; e + 4 <= n; e += 4) {
        int s0 = __builtin_amdgcn_readlane(sv, e);
        int s1 = __builtin_amdgcn_readlane(sv, e + 1);
        int s2 = __builtin_amdgcn_readlane(sv, e + 2);
        int s3 = __builtin_amdgcn_readlane(sv, e + 3);
        uint2 v = *(const uint2*)(h1b + (size_t)s0 * HID + lane * 4);
        uint2 w = *(const uint2*)(h1b + (size_t)s1 * HID + lane * 4);
        uint2 y = *(const uint2*)(h1b + (size_t)s2 * HID + lane * 4);
        uint2 zz = *(const uint2*)(h1b + (size_t)s3 * HID + lane * 4);
        a0 += bf2f((u16)v.x); a1 += bf2f((u16)(v.x >> 16));
        a2 += bf2f((u16)v.y); a3 += bf2f((u16)(v.y >> 16));
        b0 += bf2f((u16)w.x); b1 += bf2f((u16)(w.x >> 16));
        b2 += bf2f((u16)w.y); b3 += bf2f((u16)(w.y >> 16));
        c0 += bf2f((u16)y.x); c1 += bf2f((u16)(y.x >> 16));
        c2 += bf2f((u16)y.y); c3 += bf2f((u16)(y.y >> 16));
        d0 += bf2f((u16)zz.x); d1 += bf2f((u16)(zz.x >> 16));
        d2 += bf2f((u16)zz.y); d3 += bf2f((u16)(zz.y >> 16));
    }
    for (; e < n; e++) {
        int s0 = __builtin_amdgcn_readlane(sv, e);
        uint2 v = *(const uint2*)(h1b + (size_t)s0 * HID + lane * 4);
        a0 += bf2f((u16)v.x); a1 += bf2f((u16)(v.x >> 16));
        a2 += bf2f((u16)v.y); a3 += bf2f((u16)(v.y >> 16));
    }
    for (e = 64; e < dg; e++) {                      // rare tail
        int s0 = srcs2[start + e];
        uint2 v = *(const uint2*)(h1b + (size_t)s0 * HID + lane * 4);
        a0 += bf2f((u16)v.x); a1 += bf2f((u16)(v.x >> 16));
        a2 += bf2f((u16)v.y); a3 += bf2f((u16)(v.y >> 16));
    }
    float inv = 1.f / fmaxf((float)dg, 1.f);
    float r0 = (a0 + b0) + (c0 + d0);
    float r1 = (a1 + b1) + (c1 + d1);
    float r2 = (a2 + b2) + (c2 + d2);
    float r3 = (a3 + b3) + (c3 + d3);
    u32 o0 = (u32)f2bf(r0 * inv) | ((u32)f2bf(r1 * inv) << 16);
    u32 o1 = (u32)f2bf(r2 * inv) | ((u32)f2bf(r3 * inv) << 16);
    u16* p = aggb + (size_t)wid * HID + lane * 4;
    *(u32*)p = o0;
    *(u32*)(p + 2) = o1;
}

// ---------------- unified LDS-staged MFMA GEMM ----------------
// BM=64 rows/block, full N in block, BK=64, double-buffered LDS staged via
// global_load_lds(16B). XOR-8 chunk swizzle: slot s holds global chunk s^(row&7)
// -> conflict-free ds_read_b128 fragment reads.
// MODE 1: h1 = tanh(norm(agg1@W1l + x@W1r + b1) + x@Ws + bs)           -> outb
// MODE 2: h2 = tanh(norm(agg2@W2l + h1@W2r + b2)); out = h2@Wo^T + bo  -> outv
//         (final GEMM fused into the epilogue: h2 tile -> swizzled LDS,
//          Wo staged in two 32KB halves into the freed B arena)
template<int MODE>
__global__ __launch_bounds__(256, 2) void gemm_staged(
    const u16* __restrict__ A0, const u16* __restrict__ A1,
    const u16* __restrict__ W0, const u16* __restrict__ W1,
    const float* __restrict__ bias0, const float* __restrict__ bias1,
    u16* __restrict__ outb, void* __restrict__ outv, const int* __restrict__ flags) {

    constexpr int NT  = 4;                         // n-tiles per wave
    constexpr int Nw  = NT * 16;                   // cols per wave
    constexpr int NKS = (MODE == 1) ? 6 : 8;
    constexpr int BBYTES = NT * 64 * 128;          // B-tile bytes per buffer (32 KB)
    __shared__ __align__(16) u8 ldsmem[16384 + 2 * BBYTES];

    int tid = threadIdx.x;
    int w = tid >> 6, lane = tid & 63;
    int q = lane >> 4, c = lane & 15;
    int m_base = blockIdx.x * 64;
    int rj = lane >> 3, jj = lane & 7;
    int j16 = ((jj ^ rj) << 4);                    // swizzled global chunk offset

    f32x4 acc[4][NT], acc2[4][NT];
    const f32x4 z = {0.f, 0.f, 0.f, 0.f};
#pragma unroll
    for (int mt = 0; mt < 4; mt++)
#pragma unroll
        for (int nt = 0; nt < NT; nt++) { acc[mt][nt] = z; acc2[mt][nt] = z; }

    auto stage = [&](int ks, int b) {
        const u16* ap; int astr, kta;
        const u16* wp; int wstr, ktw;
        if (MODE == 1) {
            astr = 128;
            if (ks < 2)      { ap = A0; kta = ks; }
            else if (ks < 4) { ap = A1; kta = ks - 2; }
            else             { ap = A1; kta = ks - 4; }
            if (ks < 4) { wp = W0; wstr = 256; ktw = ks; }
            else        { wp = W1; wstr = 128; ktw = ks - 4; }
        } else {
            astr = 256;
            if (ks < 4) { ap = A0; kta = ks; } else { ap = A1; kta = ks - 4; }
            wp = W0; wstr = 512; ktw = ks;
        }
#pragma unroll
        for (int t = 0; t < 2; t++) {               // A: 16 rows/wave
            int r = w * 16 + t * 8;
            const u8* g = (const u8*)(ap + (size_t)(m_base + r + rj) * astr) + kta * 128 + j16;
            async16(g, ldsmem + b * 8192 + r * 128);
        }
#pragma unroll
        for (int t = 0; t < NT * 2; t++) {          // B: Nw rows/wave
            int n = w * Nw + t * 8;
            const u8* g = (const u8*)(wp + (size_t)(n + rj) * wstr) + ktw * 128 + j16;
            async16(g, ldsmem + 16384 + b * BBYTES + n * 128);
        }
    };

    auto compute = [&](int b, f32x4 (*tgt)[NT]) {
        const u8* ab = ldsmem + b * 8192;
        const u8* bb = ldsmem + 16384 + b * BBYTES;
#pragma unroll
        for (int kk = 0; kk < 2; kk++) {
            int sA = (((kk * 4 + q) ^ (c & 7)) << 4);
            short8 af[4], bfr[NT];
#pragma unroll
            for (int mt = 0; mt < 4; mt++)
                af[mt] = *(const short8*)(ab + (mt * 16 + c) * 128 + sA);
#pragma unroll
            for (int nt = 0; nt < NT; nt++)
                bfr[nt] = *(const short8*)(bb + (w * Nw + nt * 16 + c) * 128 + sA);
#pragma unroll
            for (int mt = 0; mt < 4; mt++)
#pragma unroll
                for (int nt = 0; nt < NT; nt++)
                    tgt[mt][nt] = __builtin_amdgcn_mfma_f32_16x16x32_bf16(af[mt], bfr[nt], tgt[mt][nt], 0, 0, 0);
        }
    };

    stage(0, 0);
    int b = 0;
#pragma unroll
    for (int ks = 0; ks < NKS; ks++) {
        __syncthreads();                  // drains staging of buffer b (vmcnt 0)
        if (ks + 1 < NKS) stage(ks + 1, b ^ 1);
        if (MODE == 1 && ks >= 4) compute(b, acc2);
        else                      compute(b, acc);
        b ^= 1;
    }
    __syncthreads();

    // ---------------- epilogue ----------------
    float* redf = (float*)ldsmem;         // reuse A arena: red[64][4] + invn[64]
    float bcol[NT];
#pragma unroll
    for (int nt = 0; nt < NT; nt++) bcol[nt] = bias0[w * Nw + nt * 16 + c];
    float s[4][4];
#pragma unroll
    for (int mt = 0; mt < 4; mt++)
#pragma unroll
        for (int r = 0; r < 4; r++) {
            float t = 0.f;
#pragma unroll
            for (int nt = 0; nt < NT; nt++) {
                float v = acc[mt][nt][r] + bcol[nt];
                acc[mt][nt][r] = v;
                t += v * v;
            }
            s[mt][r] = t;
        }
#pragma unroll
    for (int off = 1; off < 16; off <<= 1) {
#pragma unroll
        for (int mt = 0; mt < 4; mt++)
#pragma unroll
            for (int r = 0; r < 4; r++)
                s[mt][r] += __shfl_xor(s[mt][r], off, 64);
    }
    if (c == 0) {
#pragma unroll
        for (int mt = 0; mt < 4; mt++)
#pragma unroll
            for (int r = 0; r < 4; r++)
                redf[(mt * 16 + q * 4 + r) * 4 + w] = s[mt][r];
    }
    __syncthreads();
    if (tid < 64) {
        float t = redf[tid * 4] + redf[tid * 4 + 1] + redf[tid * 4 + 2] + redf[tid * 4 + 3];
        redf[256 + tid] = 1.f / fmaxf(sqrtf(t), 1e-12f);
    }
    __syncthreads();

    if (MODE == 1) {
        float b2col[NT];
#pragma unroll
        for (int nt = 0; nt < NT; nt++) b2col[nt] = bias1[w * Nw + nt * 16 + c];
#pragma unroll
        for (int mt = 0; mt < 4; mt++)
#pragma unroll
            for (int r = 0; r < 4; r++) {
                int rl = mt * 16 + q * 4 + r;
                int row = m_base + rl;
                if (row < N_NODES) {
                    float iv = redf[256 + rl];
#pragma unroll
                    for (int nt = 0; nt < NT; nt++) {
                        int col = w * Nw + nt * 16 + c;
                        float t = fast_tanh(acc[mt][nt][r] * iv + acc2[mt][nt][r] + b2col[nt]);
                        float tp = __shfl_xor(t, 1, 64);     // pair cols (c, c+1)
                        if (!(lane & 1)) {
                            u32 pk = (u32)f2bf(t) | ((u32)f2bf(tp) << 16);
                            *(u32*)(outb + (size_t)row * HID + col) = pk;
                        }
                    }
                }
            }
    } else {
        // -------- fused final GEMM: out = h2 @ Wo^T + bo --------
        // h2 tile [64 rows][256 k] bf16 in LDS (chunk16 XOR row&7 swizzle);
        // Wo (=W1, [128][256]) staged in two 64-row halves into the freed B arena.
        u8* h2l = ldsmem + 16384;
        u8* wol = ldsmem + 16384 + BBYTES;
        int rj2 = lane >> 5, s5 = lane & 31;

        auto stageWo = [&](int half) {
#pragma unroll
            for (int t = 0; t < 8; t++) {            // 2 rows (512B each) per async16
                int rl = w * 16 + t * 2 + rj2;
                const u8* g = (const u8*)W1 + (((size_t)(half * 64 + rl)) << 9)
                            + ((s5 ^ (rl & 7)) << 4);
                async16(g, wol + (w * 16 + t * 2) * 512);
            }
        };

        stageWo(0);                                  // loads fly under tanh VALU
#pragma unroll
        for (int mt = 0; mt < 4; mt++)
#pragma unroll
            for (int r = 0; r < 4; r++) {
                int rl = mt * 16 + q * 4 + r;
                float iv = redf[256 + rl];
#pragma unroll
                for (int nt = 0; nt < NT; nt++) {
                    int k = w * Nw + nt * 16 + c;
                    float t = fast_tanh(acc[mt][nt][r] * iv);
                    float tp = __shfl_xor(t, 1, 64);
                    if (!(lane & 1)) {               // even lane packs (k, k+1)
                        u32 pk = (u32)f2bf(t) | ((u32)f2bf(tp) << 16);
                        int off = rl * 512 + ((((k >> 3) ^ (rl & 7)) << 4)) + ((k & 7) << 1);
                        *(u32*)(h2l + off) = pk;
                    }
                }
            }
        __syncthreads();                             // h2 visible + Wo half0 staged

        int isbf = flags[0];
        float bO0 = bias1[w * 16 + c];
        float bO1 = bias1[64 + w * 16 + c];

        auto computeO = [&](f32x4* accO) {
#pragma unroll
            for (int kk = 0; kk < 8; kk++) {
                int sw = (((kk * 4 + q) ^ (c & 7)) << 4);
                short8 bfO = *(const short8*)(wol + (w * 16 + c) * 512 + sw);
#pragma unroll
                for (int mt = 0; mt < 4; mt++) {
                    short8 afO = *(const short8*)(h2l + (mt * 16 + c) * 512 + sw);
                    accO[mt] = __builtin_amdgcn_mfma_f32_16x16x32_bf16(afO, bfO, accO[mt], 0, 0, 0);
                }
            }
        };
        auto storeO = [&](int half, float bO, f32x4* accO) {
#pragma unroll
            for (int mt = 0; mt < 4; mt++)
#pragma unroll
                for (int r = 0; r < 4; r++) {
                    int row = m_base + mt * 16 + q * 4 + r;
                    if (row < N_NODES) {
                        int col = half * 64 + w * 16 + c;
                        float v = accO[mt][r] + bO;
                        if (isbf) {
                            float vp = __shfl_xor(v, 1, 64);
                            if (!(lane & 1))
                                *(u32*)((u16*)outv + (size_t)row * OUT_CH + col) =
                                    (u32)f2bf(v) | ((u32)f2bf(vp) << 16);
                        } else {
                            ((float*)outv)[(size_t)row * OUT_CH + col] = v;
                        }
                    }
                }
        };

        f32x4 accO[4];
#pragma unroll
        for (int mt = 0; mt < 4; mt++) accO[mt] = z;
        computeO(accO);                              // cols 0..63
        __syncthreads();                             // done reading Wo half0
        stageWo(1);
        storeO(0, bO0, accO);                        // store overlaps half1 staging
        __syncthreads();                             // Wo half1 staged
#pragma unroll
        for (int mt = 0; mt < 4; mt++) accO[mt] = z;
        computeO(accO);                              // cols 64..127
        storeO(1, bO1, accO);
    }
}

extern "C" void kernel_launch(void* const* d_in, const int* in_sizes, int n_in,
                              void* d_out, int out_size, void* d_ws, size_t ws_size,
                              hipStream_t stream) {
    const void* x    = d_in[0];
    const int*  ei   = (const int*)d_in[1];
    const void* em   = d_in[2];
    const void* W1l  = d_in[3];
    const void* b1   = d_in[4];
    const void* W1r  = d_in[5];
    const void* Ws   = d_in[6];
    const void* bs   = d_in[7];
    const void* W2l  = d_in[8];
    const void* b2   = d_in[9];
    const void* W2r  = d_in[10];
    const void* Wo   = d_in[11];
    const void* bo   = d_in[12];

    char* p = (char*)d_ws;
    auto carve = [&](size_t bytes) { char* r = p; p += (bytes + 63) & ~(size_t)63; return r; };
    int*   flags   = (int*)carve(256);
    u16*   xb      = (u16*)carve((size_t)N_PAD * IN_CH * 2);
    u16*   h1b     = (u16*)carve((size_t)N_PAD * HID * 2);
    u16*   aggb    = (u16*)carve((size_t)N_PAD * HID * 2);   // layer1 view: [N_PAD][128]
    u16*   Wc1     = (u16*)carve(256 * 256 * 2);
    u16*   Wsb     = (u16*)carve(256 * 128 * 2);
    u16*   Wc2     = (u16*)carve(256 * 512 * 2);
    u16*   Wob     = (u16*)carve(128 * 256 * 2);
    float* biasf   = (float*)carve(896 * 4);   // [b1|bs|b2|bo]
    u32*   degp    = (u32*)carve(50176 * 4);
    int*   row_ptr = (int*)carve(50056 * 4);
    int*   row_ptr2= (int*)carve(50056 * 4);
    u32*   partial = (u32*)carve(256 * 4);
    int*   pscan   = (int*)carve(512 * 4);
    u32*   rankp   = (u32*)carve((size_t)N_EDGES * 4);
    int*   srcs    = (int*)carve((size_t)N_EDGES * 4);
    int*   srcs2   = (int*)carve((size_t)N_EDGES * 4);
    float* b1f = biasf, *bsf = biasf + 256, *b2f = biasf + 512, *bof = biasf + 768;
    (void)ws_size; (void)in_sizes; (void)n_in; (void)out_size;

    detect_kernel<<<1, 64, 0, stream>>>((const u16*)x, (const u8*)em, flags);

    // fused conversions: x + weight concats + biases + degp zeroing, one launch
    convert_all_kernel<<<(CONV_TOTAL + 255) / 256, 256, 0, stream>>>(
        x, W1l, W1r, Ws, W2l, W2r, Wo, b1, bs, b2, bo,
        xb, Wc1, Wsb, Wc2, Wob, biasf, degp, flags);

    // ---- dual CSR build (packed histogram: one atomic per edge) ----
    hist_kernel<<<(N_EDGES + 255) / 256, 256, 0, stream>>>(ei, em, degp, rankp, flags);
    const int NB = (N_NODES + 255) / 256;   // 196
    partial_kernel<<<NB, 256, 0, stream>>>(degp, partial);
    scanp_kernel<<<1, 256, 0, stream>>>(partial, pscan, NB);
    rowptr_kernel<<<NB, 256, 0, stream>>>(degp, pscan, row_ptr, row_ptr2, NB);
    scatter_csr_kernel<<<(N_EDGES + 255) / 256, 256, 0, stream>>>(ei, rankp, row_ptr, row_ptr2, srcs, srcs2);

    const int GB = N_PAD / 64;   // 782 blocks

    // ---- layer 1 ----
    gather1_kernel<<<(N_NODES * 64) / 256, 256, 0, stream>>>(row_ptr, srcs, xb, aggb);
    gemm_staged<1><<<GB, 256, 0, stream>>>(aggb, xb, Wc1, Wsb, b1f, bsf, h1b, nullptr, flags);

    // ---- layer 2 + fused final projection ----
    gather2_kernel<<<(N_NODES * 64) / 256, 256, 0, stream>>>(row_ptr2, srcs2, h1b, aggb);
    gemm_staged<2><<<GB, 256, 0, stream>>>(aggb, h1b, Wc2, Wob, b2f, bof, nullptr, d_out, flags);
}